// Round 1
// baseline (38.037 us; speedup 1.0000x reference)
//
#include <hip/hip_runtime.h>
#include <math.h>

#define BB 32
#define CC 10
#define HH 256
#define WW 256
#define KK 500

constexpr double DEPS = 1e-7;

// shoelace area: 0.5*|sum(x_i*y_{i+1} - x_{i+1}*y_i)| (cyclic)
__device__ inline double shoelace_n(const double* x, const double* y, int n) {
    double s = 0.0;
    for (int i = 0; i < n; ++i) {
        int j = (i + 1 == n) ? 0 : i + 1;
        s += x[i] * y[j] - x[j] * y[i];
    }
    return 0.5 * fabs(s);
}

// _cal_box + _sort_ccw: build 4 corner points, sort CCW by angle around mean.
// Sort keys use atan2f (order-equivalent to ref's f32 atan2 except measure-zero ties);
// geometry kept in double.
__device__ void cal_box_sorted(const double p[8], double X[4], double Y[4]) {
    double cenx = (p[0] + p[4]) * 0.5;
    double ceny = (p[1] + p[5]) * 0.5;
    // order: tt+rr, bb+rr, bb+ll, tt+ll  (minus cen)
    double px[4] = { p[0] + p[2] - cenx, p[4] + p[2] - cenx,
                     p[4] + p[6] - cenx, p[0] + p[6] - cenx };
    double py[4] = { p[1] + p[3] - ceny, p[5] + p[3] - ceny,
                     p[5] + p[7] - ceny, p[1] + p[7] - ceny };
    double cx = (px[0] + px[1] + px[2] + px[3]) * 0.25;
    double cy = (py[0] + py[1] + py[2] + py[3]) * 0.25;
    float ang[4];
    for (int i = 0; i < 4; ++i)
        ang[i] = atan2f((float)(py[i] - cy), (float)(px[i] - cx));
    int idx[4] = {0, 1, 2, 3};
    for (int i = 1; i < 4; ++i) {          // stable insertion sort (matches stable argsort)
        int key = idx[i]; float ka = ang[key]; int j = i - 1;
        while (j >= 0 && ang[idx[j]] > ka) { idx[j + 1] = idx[j]; --j; }
        idx[j + 1] = key;
    }
    for (int i = 0; i < 4; ++i) { X[i] = px[idx[i]]; Y[i] = py[idx[i]]; }
}

__device__ double convex_inter(const double AX[4], const double AY[4],
                               const double BX[4], const double BY[4],
                               bool* anyv) {
    bool valid[24];
    double PX[24], PY[24];
    // mA: A points inside B
    for (int i = 0; i < 4; ++i) {
        bool ok = true;
        for (int j = 0; j < 4; ++j) {
            int jn = (j + 1) & 3;
            double ex = BX[jn] - BX[j], ey = BY[jn] - BY[j];
            double qx = AX[i] - BX[j], qy = AY[i] - BY[j];
            ok = ok && (ex * qy - ey * qx >= -DEPS);
        }
        PX[i] = AX[i]; PY[i] = AY[i]; valid[i] = ok;
    }
    // mB: B points inside A
    for (int i = 0; i < 4; ++i) {
        bool ok = true;
        for (int j = 0; j < 4; ++j) {
            int jn = (j + 1) & 3;
            double ex = AX[jn] - AX[j], ey = AY[jn] - AY[j];
            double qx = BX[i] - AX[j], qy = BY[i] - AY[j];
            ok = ok && (ex * qy - ey * qx >= -DEPS);
        }
        PX[4 + i] = BX[i]; PY[4 + i] = BY[i]; valid[4 + i] = ok;
    }
    // 16 edge-pair intersections, a-edge-major order (matches pI.reshape(16,2))
    for (int i = 0; i < 4; ++i) {
        int in_ = (i + 1) & 3;
        double a1x = AX[i], a1y = AY[i];
        double d1x = AX[in_] - a1x, d1y = AY[in_] - a1y;
        for (int j = 0; j < 4; ++j) {
            int jn = (j + 1) & 3;
            double b1x = BX[j], b1y = BY[j];
            double d2x = BX[jn] - b1x, d2y = BY[jn] - b1y;
            double den = d1x * d2y - d1y * d2x;
            double dx = b1x - a1x, dy = b1y - a1y;
            bool dok = fabs(den) > DEPS;
            double safe = dok ? den : 1.0;
            double t = (dx * d2y - dy * d2x) / safe;
            double u = (dx * d1y - dy * d1x) / safe;
            bool ok = dok && (t >= -DEPS) && (t <= 1.0 + DEPS)
                          && (u >= -DEPS) && (u <= 1.0 + DEPS);
            int kq = 8 + i * 4 + j;
            PX[kq] = a1x + t * d1x;
            PY[kq] = a1y + t * d1y;
            valid[kq] = ok;
        }
    }
    // first = pts[argmax(valid)]  (first True, else index 0)
    int fi = 0;
    for (int k = 23; k >= 0; --k) if (valid[k]) fi = k;
    int nv = 0; double sx = 0.0, sy = 0.0; bool any = false;
    for (int k = 0; k < 24; ++k)
        if (valid[k]) { ++nv; sx += PX[k]; sy += PY[k]; any = true; }
    for (int k = 0; k < 24; ++k)
        if (!valid[k]) { PX[k] = PX[fi]; PY[k] = PY[fi]; }
    int nvd = nv < 1 ? 1 : nv;
    double cx = sx / nvd, cy = sy / nvd;
    float ang[24]; int idx[24];
    for (int k = 0; k < 24; ++k) {
        ang[k] = atan2f((float)(PY[k] - cy), (float)(PX[k] - cx));
        idx[k] = k;
    }
    for (int i = 1; i < 24; ++i) {         // stable insertion sort
        int key = idx[i]; float ka = ang[key]; int j = i - 1;
        while (j >= 0 && ang[idx[j]] > ka) { idx[j + 1] = idx[j]; --j; }
        idx[j + 1] = key;
    }
    double sxx[24], syy[24];
    for (int k = 0; k < 24; ++k) { sxx[k] = PX[idx[k]]; syy[k] = PY[idx[k]]; }
    double area = shoelace_n(sxx, syy, 24);
    *anyv = any;
    return any ? area : 0.0;
}

__device__ double per_box(const double a[8], const double g[8]) {
    double AX[4], AY[4], BX[4], BY[4];
    cal_box_sorted(a, AX, AY);
    cal_box_sorted(g, BX, BY);
    bool any;
    double inter = convex_inter(AX, AY, BX, BY, &any);
    double areaA = shoelace_n(AX, AY, 4);
    double areaB = shoelace_n(BX, BY, 4);
    double uni = areaA + areaB - inter;
    double iou = (uni > 0.0) ? (inter / uni) : 0.0;
    double w  = sqrt((a[2]-a[6])*(a[2]-a[6]) + (a[3]-a[7])*(a[3]-a[7]));
    double h  = sqrt((a[0]-a[4])*(a[0]-a[4]) + (a[1]-a[5])*(a[1]-a[5]));
    // NOTE: reference uses (b[3] - a[7]) here — reproduce faithfully.
    double wt = sqrt((g[2]-g[6])*(g[2]-g[6]) + (g[3]-a[7])*(g[3]-a[7]));
    double ht = sqrt((g[0]-g[4])*(g[0]-g[4]) + (g[1]-g[5])*(g[1]-g[5]));
    double th1  = (a[3]-a[7]) / (a[2]-a[6]);
    double tth1 = (g[3]-g[7]) / (g[2]-g[6]);
    double th   = (a[1]-a[5]) / (a[0]-a[4]);
    double tth  = (g[1]-g[5]) / (g[0]-g[4]);
    double d1 = atan(th)  - atan(tth);
    double d2 = atan(th1) - atan(tth1);
    double nn = fmin(d1*d1, d2*d2);
    const double c4 = 4.0 / (M_PI * M_PI);
    double dv = atan(wt/ht) - atan(w/h);
    double v = c4 * dv * dv;
    double s = c4 * nn;
    double alpha = (v + s) / (1.0 - iou + v + s);
    return alpha * (v + 0.7 * s);
}

__global__ __launch_bounds__(1024)
void IouLoss_26766236189166_kernel(const float* __restrict__ pred_wh,
                                   const float* __restrict__ wh_target,
                                   const float* __restrict__ reg_mask,
                                   const int* __restrict__ ind,
                                   float* __restrict__ out) {
    __shared__ int s_wave[16];
    const int tid = threadIdx.x;
    // 1) find last flat index with reg_mask > 0  (16000 floats, float4-vectorized)
    int lmax = -1;
    const int N4 = (BB * KK) / 4;  // 4000
    const float4* rm = (const float4*)reg_mask;
    for (int i = tid; i < N4; i += 1024) {
        float4 v = rm[i];
        int cand = -1;
        if (v.x > 0.f) cand = 4 * i;
        if (v.y > 0.f) cand = 4 * i + 1;
        if (v.z > 0.f) cand = 4 * i + 2;
        if (v.w > 0.f) cand = 4 * i + 3;
        if (cand > lmax) lmax = cand;
    }
    #pragma unroll
    for (int off = 32; off > 0; off >>= 1)
        lmax = max(lmax, __shfl_down(lmax, off, 64));
    if ((tid & 63) == 0) s_wave[tid >> 6] = lmax;
    __syncthreads();
    if (tid != 0) return;

    int last = -1;
    #pragma unroll
    for (int w = 0; w < 16; ++w) last = max(last, s_wave[w]);

    float loss = 0.0f;
    if (last >= 0) {
        const int b = last / KK;
        const int k = last - b * KK;
        const int pix = ind[last];  // ind flat index == reg_mask flat index
        double a[8], g[8];
        const float* pw = pred_wh + (size_t)b * CC * (HH * WW) + pix;
        #pragma unroll
        for (int c = 0; c < 8; ++c) a[c] = (double)pw[(size_t)c * (HH * WW)];
        const float* gt = wh_target + ((size_t)b * KK + k) * CC;
        #pragma unroll
        for (int c = 0; c < 8; ++c) g[c] = (double)gt[c];
        loss = (float)per_box(a, g);
    }
    out[0] = loss;
}

extern "C" void kernel_launch(void* const* d_in, const int* in_sizes, int n_in,
                              void* d_out, int out_size, void* d_ws, size_t ws_size,
                              hipStream_t stream) {
    const float* pred_wh   = (const float*)d_in[0];
    const float* wh_target = (const float*)d_in[1];
    const float* reg_mask  = (const float*)d_in[2];
    const int*   ind       = (const int*)d_in[3];
    float* out = (float*)d_out;
    IouLoss_26766236189166_kernel<<<dim3(1), dim3(1024), 0, stream>>>(
        pred_wh, wh_target, reg_mask, ind, out);
}

// Round 2
// 13.305 us; speedup vs baseline: 2.8587x; 2.8587x over previous
//
#include <hip/hip_runtime.h>
#include <math.h>

#define BB 32
#define CC 10
#define HH 256
#define WW 256
#define KK 500

constexpr double DEPS = 1e-7;

__device__ inline double dshfl(double v, int lane) { return __shfl(v, lane, 64); }

// 4-point shoelace
__device__ inline double shoelace4(const double* x, const double* y) {
    double s = x[0]*y[1] - x[1]*y[0];
    s += x[1]*y[2] - x[2]*y[1];
    s += x[2]*y[3] - x[3]*y[2];
    s += x[3]*y[0] - x[0]*y[3];
    return 0.5 * fabs(s);
}

// _cal_box + _sort_ccw (f64 geometry, f32 atan2 sort keys, stable — matches jnp)
__device__ void cal_box_sorted(const double p[8], double X[4], double Y[4]) {
    double cenx = (p[0] + p[4]) * 0.5;
    double ceny = (p[1] + p[5]) * 0.5;
    double px[4] = { p[0] + p[2] - cenx, p[4] + p[2] - cenx,
                     p[4] + p[6] - cenx, p[0] + p[6] - cenx };
    double py[4] = { p[1] + p[3] - ceny, p[5] + p[3] - ceny,
                     p[5] + p[7] - ceny, p[1] + p[7] - ceny };
    double cx = (px[0] + px[1] + px[2] + px[3]) * 0.25;
    double cy = (py[0] + py[1] + py[2] + py[3]) * 0.25;
    float ang[4];
    #pragma unroll
    for (int i = 0; i < 4; ++i)
        ang[i] = atan2f((float)(py[i] - cy), (float)(px[i] - cx));
    int idx[4] = {0, 1, 2, 3};
    #pragma unroll
    for (int i = 1; i < 4; ++i) {
        int key = idx[i]; float ka = ang[key]; int j = i - 1;
        while (j >= 0 && ang[idx[j]] > ka) { idx[j + 1] = idx[j]; --j; }
        idx[j + 1] = key;
    }
    #pragma unroll
    for (int i = 0; i < 4; ++i) { X[i] = px[idx[i]]; Y[i] = py[idx[i]]; }
}

__global__ __launch_bounds__(1024)
void IouLoss_26766236189166_kernel(const float* __restrict__ pred_wh,
                                   const float* __restrict__ wh_target,
                                   const float* __restrict__ reg_mask,
                                   const int* __restrict__ ind,
                                   float* __restrict__ out) {
    __shared__ int s_wave[16];
    __shared__ int s_last;
    const int tid = threadIdx.x;

    // ---- Phase 1: last index with reg_mask>0, scanning chunks from the top
    // (early exit: with a dense mask only the top 16 KB is read) ----
    const float4* rm = (const float4*)reg_mask;
    const int N4 = (BB * KK) / 4;  // 4000
    int last = -1;
    for (int chunk = 3; chunk >= 0; --chunk) {
        int lmax = -1;
        int i = chunk * 1024 + tid;
        if (i < N4) {
            float4 v = rm[i];
            if (v.x > 0.f) lmax = 4 * i;
            if (v.y > 0.f) lmax = 4 * i + 1;
            if (v.z > 0.f) lmax = 4 * i + 2;
            if (v.w > 0.f) lmax = 4 * i + 3;
        }
        #pragma unroll
        for (int off = 32; off > 0; off >>= 1)
            lmax = max(lmax, __shfl_down(lmax, off, 64));
        if ((tid & 63) == 0) s_wave[tid >> 6] = lmax;
        __syncthreads();
        if (tid == 0) {
            int m = -1;
            #pragma unroll
            for (int w = 0; w < 16; ++w) m = max(m, s_wave[w]);
            s_last = m;
        }
        __syncthreads();
        last = s_last;
        if (last >= 0) break;   // uniform
    }

    if (tid >= 64) return;      // only wave 0 continues; no more barriers
    const int k = tid;          // lane id 0..63

    float loss = 0.0f;
    if (last >= 0) {
        const int b   = last / KK;
        const int kk_ = last - b * KK;
        const int pix = ind[last];

        // broadcast loads (all lanes, same addresses)
        double a[8], g[8];
        const float* pw = pred_wh + (size_t)b * CC * (HH * WW) + pix;
        const float* gt = wh_target + ((size_t)b * KK + kk_) * CC;
        #pragma unroll
        for (int c = 0; c < 8; ++c) a[c] = (double)pw[(size_t)c * (HH * WW)];
        #pragma unroll
        for (int c = 0; c < 8; ++c) g[c] = (double)gt[c];

        // redundant per-lane: sorted corner sets
        double AX[4], AY[4], BX[4], BY[4];
        cal_box_sorted(a, AX, AY);
        cal_box_sorted(g, BX, BY);

        // ---- per-lane candidate point k of the 24 ----
        bool valid = false; double px = 0.0, py = 0.0;
        if (k < 4) {                      // A[k] inside B?
            bool ok = true;
            #pragma unroll
            for (int j = 0; j < 4; ++j) {
                int jn = (j + 1) & 3;
                double ex = BX[jn] - BX[j], ey = BY[jn] - BY[j];
                double qx = AX[k] - BX[j], qy = AY[k] - BY[j];
                ok = ok && (ex * qy - ey * qx >= -DEPS);
            }
            valid = ok; px = AX[k]; py = AY[k];
        } else if (k < 8) {               // B[k-4] inside A?
            int i = k - 4;
            bool ok = true;
            #pragma unroll
            for (int j = 0; j < 4; ++j) {
                int jn = (j + 1) & 3;
                double ex = AX[jn] - AX[j], ey = AY[jn] - AY[j];
                double qx = BX[i] - AX[j], qy = BY[i] - AY[j];
                ok = ok && (ex * qy - ey * qx >= -DEPS);
            }
            valid = ok; px = BX[i]; py = BY[i];
        } else if (k < 24) {              // edge pair (i,j) intersection
            int i = (k - 8) >> 2, j = (k - 8) & 3;
            int in_ = (i + 1) & 3, jn = (j + 1) & 3;
            double a1x = AX[i], a1y = AY[i];
            double d1x = AX[in_] - a1x, d1y = AY[in_] - a1y;
            double b1x = BX[j], b1y = BY[j];
            double d2x = BX[jn] - b1x, d2y = BY[jn] - b1y;
            double den = d1x * d2y - d1y * d2x;
            double dx = b1x - a1x, dy = b1y - a1y;
            bool dok = fabs(den) > DEPS;
            double safe = dok ? den : 1.0;
            double t = (dx * d2y - dy * d2x) / safe;
            double u = (dx * d1y - dy * d1x) / safe;
            valid = dok && (t >= -DEPS) && (t <= 1.0 + DEPS)
                        && (u >= -DEPS) && (u <= 1.0 + DEPS);
            px = a1x + t * d1x;
            py = a1y + t * d1y;
        }

        // ---- gather stats across the 24 candidates ----
        unsigned long long mv = __ballot(valid);
        bool any = (mv != 0ull);
        int nv  = __popcll(mv);
        int nvd = nv < 1 ? 1 : nv;
        int fi  = any ? ((int)__ffsll(mv) - 1) : 0;
        double fx = dshfl(px, fi), fy = dshfl(py, fi);
        if (k < 24 && !valid) { px = fx; py = fy; }

        double cxs = valid ? px : 0.0, cys = valid ? py : 0.0;
        #pragma unroll
        for (int off = 32; off > 0; off >>= 1) {
            cxs += __shfl_xor(cxs, off, 64);
            cys += __shfl_xor(cys, off, 64);
        }
        double cx = cxs / (double)nvd, cy = cys / (double)nvd;

        // stable rank by f32 angle (ties broken by original index, = jnp stable argsort)
        float ang = (k < 24) ? atan2f((float)(py - cy), (float)(px - cx)) : INFINITY;
        int r = 0;
        #pragma unroll
        for (int j = 0; j < 24; ++j) {
            float aj = __shfl(ang, j, 64);
            r += (aj < ang) || (aj == ang && j < k);
        }
        if (k >= 24) r = k;   // identity for inert lanes (unique dests)

        // scatter points to rank-order lanes
        int addr = r << 2;
        int xlo = __builtin_amdgcn_ds_permute(addr, __double2loint(px));
        int xhi = __builtin_amdgcn_ds_permute(addr, __double2hiint(px));
        int ylo = __builtin_amdgcn_ds_permute(addr, __double2loint(py));
        int yhi = __builtin_amdgcn_ds_permute(addr, __double2hiint(py));
        double sxp = __hiloint2double(xhi, xlo);
        double syp = __hiloint2double(yhi, ylo);

        // cyclic shoelace over the 24 sorted points
        int nxt = (k < 23) ? (k + 1) : ((k == 23) ? 0 : k);
        double nx = dshfl(sxp, nxt);
        double ny = dshfl(syp, nxt);
        double term = (k < 24) ? (sxp * ny - nx * syp) : 0.0;
        #pragma unroll
        for (int off = 32; off > 0; off >>= 1)
            term += __shfl_xor(term, off, 64);
        double inter = any ? 0.5 * fabs(term) : 0.0;

        // ---- final loss (redundant per lane; atans lane-parallel) ----
        double areaA = shoelace4(AX, AY);
        double areaB = shoelace4(BX, BY);
        double uni = areaA + areaB - inter;
        double iou = (uni > 0.0) ? (inter / uni) : 0.0;

        double w  = sqrt((a[2]-a[6])*(a[2]-a[6]) + (a[3]-a[7])*(a[3]-a[7]));
        double h  = sqrt((a[0]-a[4])*(a[0]-a[4]) + (a[1]-a[5])*(a[1]-a[5]));
        // NOTE: reference uses (b[3] - a[7]) here — reproduced faithfully.
        double wt = sqrt((g[2]-g[6])*(g[2]-g[6]) + (g[3]-a[7])*(g[3]-a[7]));
        double ht = sqrt((g[0]-g[4])*(g[0]-g[4]) + (g[1]-g[5])*(g[1]-g[5]));

        // lane-selected numerator/denominator: one f64 div + one f64 atan per lane
        double num = (k==0) ? (a[1]-a[5]) : (k==1) ? (g[1]-g[5]) :
                     (k==2) ? (a[3]-a[7]) : (k==3) ? (g[3]-g[7]) :
                     (k==4) ? wt : w;
        double den = (k==0) ? (a[0]-a[4]) : (k==1) ? (g[0]-g[4]) :
                     (k==2) ? (a[2]-a[6]) : (k==3) ? (g[2]-g[6]) :
                     (k==4) ? ht : h;
        double at = atan(num / den);
        double t_th   = dshfl(at, 0);
        double t_tth  = dshfl(at, 1);
        double t_th1  = dshfl(at, 2);
        double t_tth1 = dshfl(at, 3);
        double t_awt  = dshfl(at, 4);
        double t_aw   = dshfl(at, 5);

        double d1v = t_th  - t_tth;
        double d2v = t_th1 - t_tth1;
        double nn = fmin(d1v * d1v, d2v * d2v);
        const double c4 = 4.0 / (M_PI * M_PI);
        double dvv = t_awt - t_aw;
        double v = c4 * dvv * dvv;
        double sv = c4 * nn;
        double alpha = (v + sv) / (1.0 - iou + v + sv);
        loss = (float)(alpha * (v + 0.7 * sv));
    }

    if (tid == 0) out[0] = loss;
}

extern "C" void kernel_launch(void* const* d_in, const int* in_sizes, int n_in,
                              void* d_out, int out_size, void* d_ws, size_t ws_size,
                              hipStream_t stream) {
    const float* pred_wh   = (const float*)d_in[0];
    const float* wh_target = (const float*)d_in[1];
    const float* reg_mask  = (const float*)d_in[2];
    const int*   ind       = (const int*)d_in[3];
    float* out = (float*)d_out;
    IouLoss_26766236189166_kernel<<<dim3(1), dim3(1024), 0, stream>>>(
        pred_wh, wh_target, reg_mask, ind, out);
}

// Round 3
// 12.576 us; speedup vs baseline: 3.0245x; 1.0580x over previous
//
#include <hip/hip_runtime.h>
#include <math.h>

#define BB 32
#define CC 10
#define HH 256
#define WW 256
#define KK 500

constexpr double DEPS = 1e-7;

__device__ inline double dshfl(double v, int lane) { return __shfl(v, lane, 64); }

// 4-point shoelace
__device__ inline double shoelace4(const double* x, const double* y) {
    double s = x[0]*y[1] - x[1]*y[0];
    s += x[1]*y[2] - x[2]*y[1];
    s += x[2]*y[3] - x[3]*y[2];
    s += x[3]*y[0] - x[0]*y[3];
    return 0.5 * fabs(s);
}

// _cal_box + _sort_ccw (f64 geometry, f32 atan2 sort keys, stable — matches jnp)
__device__ void cal_box_sorted(const double p[8], double X[4], double Y[4]) {
    double cenx = (p[0] + p[4]) * 0.5;
    double ceny = (p[1] + p[5]) * 0.5;
    double px[4] = { p[0] + p[2] - cenx, p[4] + p[2] - cenx,
                     p[4] + p[6] - cenx, p[0] + p[6] - cenx };
    double py[4] = { p[1] + p[3] - ceny, p[5] + p[3] - ceny,
                     p[5] + p[7] - ceny, p[1] + p[7] - ceny };
    double cx = (px[0] + px[1] + px[2] + px[3]) * 0.25;
    double cy = (py[0] + py[1] + py[2] + py[3]) * 0.25;
    float ang[4];
    #pragma unroll
    for (int i = 0; i < 4; ++i)
        ang[i] = atan2f((float)(py[i] - cy), (float)(px[i] - cx));
    int idx[4] = {0, 1, 2, 3};
    #pragma unroll
    for (int i = 1; i < 4; ++i) {
        int key = idx[i]; float ka = ang[key]; int j = i - 1;
        while (j >= 0 && ang[idx[j]] > ka) { idx[j + 1] = idx[j]; --j; }
        idx[j + 1] = key;
    }
    #pragma unroll
    for (int i = 0; i < 4; ++i) { X[i] = px[idx[i]]; Y[i] = py[idx[i]]; }
}

__global__ __launch_bounds__(64)
void IouLoss_26766236189166_kernel(const float* __restrict__ pred_wh,
                                   const float* __restrict__ wh_target,
                                   const float* __restrict__ reg_mask,
                                   const int* __restrict__ ind,
                                   float* __restrict__ out) {
    const int k = threadIdx.x;           // single wave, lane 0..63
    const float4* rm = (const float4*)reg_mask;
    const int4*   iv = (const int4*)ind;
    const int N4 = (BB * KK) / 4;        // 4000

    // ---- Phase 1: last index with reg_mask>0, scanning 256 elems/iter from
    // the top; co-load ind so the winner's pix rides the same reduce ----
    int last = -1, pix = 0;
    for (int base = N4 - 64; base > -64; base -= 64) {
        int i = base + k;
        int lmax = -1, pcand = 0;
        if (i >= 0) {
            float4 v = rm[i];
            int4  iq = iv[i];
            if (v.x > 0.f) { lmax = 4*i;     pcand = iq.x; }
            if (v.y > 0.f) { lmax = 4*i + 1; pcand = iq.y; }
            if (v.z > 0.f) { lmax = 4*i + 2; pcand = iq.z; }
            if (v.w > 0.f) { lmax = 4*i + 3; pcand = iq.w; }
        }
        unsigned long long packed =
            ((unsigned long long)(unsigned)(lmax + 1) << 32) | (unsigned)pcand;
        #pragma unroll
        for (int off = 32; off > 0; off >>= 1) {
            unsigned long long o = __shfl_xor(packed, off, 64);
            packed = (o > packed) ? o : packed;
        }
        if ((packed >> 32) != 0ull) {    // uniform after butterfly
            last = (int)(packed >> 32) - 1;
            pix  = (int)(packed & 0xffffffffull);
            break;
        }
    }

    float loss = 0.0f;
    if (last >= 0) {
        const int b   = last / KK;
        const int kk_ = last - b * KK;

        // broadcast loads (all lanes, same addresses); all independent
        double a[8], g[8];
        const float* pw = pred_wh + (size_t)b * CC * (HH * WW) + pix;
        const float* gt = wh_target + ((size_t)b * KK + kk_) * CC;
        #pragma unroll
        for (int c = 0; c < 8; ++c) a[c] = (double)pw[(size_t)c * (HH * WW)];
        #pragma unroll
        for (int c = 0; c < 8; ++c) g[c] = (double)gt[c];

        // redundant per-lane: sorted corner sets
        double AX[4], AY[4], BX[4], BY[4];
        cal_box_sorted(a, AX, AY);
        cal_box_sorted(g, BX, BY);

        // ---- per-lane candidate point k of the 24 ----
        bool valid = false; double px = 0.0, py = 0.0;
        if (k < 4) {                      // A[k] inside B?
            bool ok = true;
            #pragma unroll
            for (int j = 0; j < 4; ++j) {
                int jn = (j + 1) & 3;
                double ex = BX[jn] - BX[j], ey = BY[jn] - BY[j];
                double qx = AX[k] - BX[j], qy = AY[k] - BY[j];
                ok = ok && (ex * qy - ey * qx >= -DEPS);
            }
            valid = ok; px = AX[k]; py = AY[k];
        } else if (k < 8) {               // B[k-4] inside A?
            int i = k - 4;
            bool ok = true;
            #pragma unroll
            for (int j = 0; j < 4; ++j) {
                int jn = (j + 1) & 3;
                double ex = AX[jn] - AX[j], ey = AY[jn] - AY[j];
                double qx = BX[i] - AX[j], qy = BY[i] - AY[j];
                ok = ok && (ex * qy - ey * qx >= -DEPS);
            }
            valid = ok; px = BX[i]; py = BY[i];
        } else if (k < 24) {              // edge pair (i,j) intersection
            int i = (k - 8) >> 2, j = (k - 8) & 3;
            int in_ = (i + 1) & 3, jn = (j + 1) & 3;
            double a1x = AX[i], a1y = AY[i];
            double d1x = AX[in_] - a1x, d1y = AY[in_] - a1y;
            double b1x = BX[j], b1y = BY[j];
            double d2x = BX[jn] - b1x, d2y = BY[jn] - b1y;
            double den = d1x * d2y - d1y * d2x;
            double dx = b1x - a1x, dy = b1y - a1y;
            bool dok = fabs(den) > DEPS;
            double safe = dok ? den : 1.0;
            double t = (dx * d2y - dy * d2x) / safe;
            double u = (dx * d1y - dy * d1x) / safe;
            valid = dok && (t >= -DEPS) && (t <= 1.0 + DEPS)
                        && (u >= -DEPS) && (u <= 1.0 + DEPS);
            px = a1x + t * d1x;
            py = a1y + t * d1y;
        }

        // ---- gather stats across the 24 candidates ----
        unsigned long long mv = __ballot(valid);
        bool any = (mv != 0ull);
        int nv  = __popcll(mv);
        int nvd = nv < 1 ? 1 : nv;
        int fi  = any ? ((int)__ffsll(mv) - 1) : 0;
        double fx = dshfl(px, fi), fy = dshfl(py, fi);
        if (k < 24 && !valid) { px = fx; py = fy; }

        double cxs = valid ? px : 0.0, cys = valid ? py : 0.0;
        #pragma unroll
        for (int off = 32; off > 0; off >>= 1) {
            cxs += __shfl_xor(cxs, off, 64);
            cys += __shfl_xor(cys, off, 64);
        }
        double cx = cxs / (double)nvd, cy = cys / (double)nvd;

        // stable rank by f32 angle (ties broken by original index, = jnp stable argsort)
        float ang = (k < 24) ? atan2f((float)(py - cy), (float)(px - cx)) : INFINITY;
        int r = 0;
        #pragma unroll
        for (int j = 0; j < 24; ++j) {
            float aj = __shfl(ang, j, 64);
            r += (aj < ang) || (aj == ang && j < k);
        }
        if (k >= 24) r = k;   // identity for inert lanes (unique dests)

        // scatter points to rank-order lanes
        int addr = r << 2;
        int xlo = __builtin_amdgcn_ds_permute(addr, __double2loint(px));
        int xhi = __builtin_amdgcn_ds_permute(addr, __double2hiint(px));
        int ylo = __builtin_amdgcn_ds_permute(addr, __double2loint(py));
        int yhi = __builtin_amdgcn_ds_permute(addr, __double2hiint(py));
        double sxp = __hiloint2double(xhi, xlo);
        double syp = __hiloint2double(yhi, ylo);

        // cyclic shoelace over the 24 sorted points
        int nxt = (k < 23) ? (k + 1) : ((k == 23) ? 0 : k);
        double nx = dshfl(sxp, nxt);
        double ny = dshfl(syp, nxt);
        double term = (k < 24) ? (sxp * ny - nx * syp) : 0.0;
        #pragma unroll
        for (int off = 32; off > 0; off >>= 1)
            term += __shfl_xor(term, off, 64);
        double inter = any ? 0.5 * fabs(term) : 0.0;

        // ---- final loss (redundant per lane; atans lane-parallel) ----
        double areaA = shoelace4(AX, AY);
        double areaB = shoelace4(BX, BY);
        double uni = areaA + areaB - inter;
        double iou = (uni > 0.0) ? (inter / uni) : 0.0;

        double w  = sqrt((a[2]-a[6])*(a[2]-a[6]) + (a[3]-a[7])*(a[3]-a[7]));
        double h  = sqrt((a[0]-a[4])*(a[0]-a[4]) + (a[1]-a[5])*(a[1]-a[5]));
        // NOTE: reference uses (b[3] - a[7]) here — reproduced faithfully.
        double wt = sqrt((g[2]-g[6])*(g[2]-g[6]) + (g[3]-a[7])*(g[3]-a[7]));
        double ht = sqrt((g[0]-g[4])*(g[0]-g[4]) + (g[1]-g[5])*(g[1]-g[5]));

        // lane-selected numerator/denominator: one f64 div + one f64 atan per lane
        double num = (k==0) ? (a[1]-a[5]) : (k==1) ? (g[1]-g[5]) :
                     (k==2) ? (a[3]-a[7]) : (k==3) ? (g[3]-g[7]) :
                     (k==4) ? wt : w;
        double den = (k==0) ? (a[0]-a[4]) : (k==1) ? (g[0]-g[4]) :
                     (k==2) ? (a[2]-a[6]) : (k==3) ? (g[2]-g[6]) :
                     (k==4) ? ht : h;
        double at = atan(num / den);
        double t_th   = dshfl(at, 0);
        double t_tth  = dshfl(at, 1);
        double t_th1  = dshfl(at, 2);
        double t_tth1 = dshfl(at, 3);
        double t_awt  = dshfl(at, 4);
        double t_aw   = dshfl(at, 5);

        double d1v = t_th  - t_tth;
        double d2v = t_th1 - t_tth1;
        double nn = fmin(d1v * d1v, d2v * d2v);
        const double c4 = 4.0 / (M_PI * M_PI);
        double dvv = t_awt - t_aw;
        double v = c4 * dvv * dvv;
        double sv = c4 * nn;
        double alpha = (v + sv) / (1.0 - iou + v + sv);
        loss = (float)(alpha * (v + 0.7 * sv));
    }

    if (k == 0) out[0] = loss;
}

extern "C" void kernel_launch(void* const* d_in, const int* in_sizes, int n_in,
                              void* d_out, int out_size, void* d_ws, size_t ws_size,
                              hipStream_t stream) {
    const float* pred_wh   = (const float*)d_in[0];
    const float* wh_target = (const float*)d_in[1];
    const float* reg_mask  = (const float*)d_in[2];
    const int*   ind       = (const int*)d_in[3];
    float* out = (float*)d_out;
    IouLoss_26766236189166_kernel<<<dim3(1), dim3(64), 0, stream>>>(
        pred_wh, wh_target, reg_mask, ind, out);
}